// Round 10
// baseline (21.432 us; speedup 1.0000x reference)
//
#include <hip/hip_runtime.h>

#define BLOCK  256
#define IPT    8                  // i's per thread (independent acc chains)
#define ITILE  (BLOCK * IPT)      // 2048 i's per block
#define TJ     64                 // j-chunk per block
#define TSCALE 32.0f              // > max possible |1 - pj + pi| (~9)
#define NHB    16                 // histogram blocks (placed last in grid)
#define NBIN   20                 // targets in [0, 20)

typedef float vf2 __attribute__((ext_vector_type(2)));

// kernel 1: blocks [0,npair) pair tiles; blocks [npair, npair+NHB) histogram.
// All outputs plain stores -> no memset / atomics anywhere.
__global__ __launch_bounds__(BLOCK) void prl_main(
    const float* __restrict__ pred, const int* __restrict__ targ,
    int n, int gx, int npair,
    float* __restrict__ partials,     // [npair]
    int*   __restrict__ hist)         // [NHB * NBIN]
{
    const int tid = threadIdx.x;

    if ((int)blockIdx.x >= npair) {
        // ---------- ballot-popcount histogram block (no atomics) ----------
        const int hb   = blockIdx.x - npair;
        const int wave = tid >> 6;
        const int lane = tid & 63;

        int c[NBIN];
        #pragma unroll
        for (int v = 0; v < NBIN; ++v) c[v] = 0;

        const int CHUNK = NHB * BLOCK * 2;            // 8192: one iter for n=8192
        const int iters = (n + CHUNK - 1) / CHUNK;
        for (int it = 0; it < iters; ++it) {
            const int i0 = it * CHUNK + hb * BLOCK * 2 + tid * 2;
            const int t0 = (i0     < n) ? targ[i0]     : -1;
            const int t1 = (i0 + 1 < n) ? targ[i0 + 1] : -1;
            #pragma unroll
            for (int v = 0; v < NBIN; ++v)
                c[v] += __popcll(__ballot(t0 == v)) + __popcll(__ballot(t1 == v));
        }

        __shared__ int whist[BLOCK / 64][NBIN];
        if (lane == 0) {
            #pragma unroll
            for (int v = 0; v < NBIN; ++v) whist[wave][v] = c[v];
        }
        __syncthreads();
        if (tid < NBIN) {
            int h = 0;
            #pragma unroll
            for (int w = 0; w < BLOCK / 64; ++w) h += whist[w][tid];
            hist[hb * NBIN + tid] = h;                 // plain store
        }
    } else {
        // ---------- pair tile block: v_pk_add_f32 packed inner loop ----------
        __shared__ vf2  sq2[TJ / 2];         // q = 1 - pj, 2 j's per entry
        __shared__ vf2  sF2[TJ / 2];         // F = q + 32*tj - 32
        __shared__ float wsum[BLOCK / 64];

        const int bx = blockIdx.x % gx;
        const int by = blockIdx.x / gx;
        const int i0 = bx * ITILE;
        const int j0 = by * TJ;

        vf2 pi2[IPT], Ei2[IPT], s2[IPT];
        #pragma unroll
        for (int m = 0; m < IPT; ++m) {
            const int i = i0 + m * BLOCK + tid;
            float p, E;
            if (i < n) {
                p = pred[i];
                E = __fmaf_rn(-TSCALE, (float)targ[i], p);     // p - 32*t
            } else {
                p = 0.0f; E = -1.0e9f;                         // never contributes
            }
            pi2[m] = (vf2){p, p};
            Ei2[m] = (vf2){E, E};
            s2[m]  = (vf2){0.0f, 0.0f};
        }

        if (tid < TJ) {
            const int j = j0 + tid;
            float q, F;
            if (j < n) {
                const float pj = pred[j];
                q = 1.0f - pj;
                F = __fmaf_rn(TSCALE, (float)targ[j], q - TSCALE); // q + 32*t - 32
            } else {
                q = 0.0f; F = -1.0e9f;                             // never contributes
            }
            ((float*)sq2)[tid] = q;
            ((float*)sF2)[tid] = F;
        }
        __syncthreads();

        #pragma unroll
        for (int kk = 0; kk < TJ / 2; ++kk) {
            const vf2 q2 = sq2[kk];            // ds_read_b64
            const vf2 F2 = sF2[kk];            // ds_read_b64
            #pragma unroll
            for (int m = 0; m < IPT; ++m) {
                vf2 g2, x2, h2;
                asm("v_pk_add_f32 %0, %1, %2" : "=v"(g2) : "v"(Ei2[m]), "v"(F2));
                asm("v_pk_add_f32 %0, %1, %2" : "=v"(x2) : "v"(pi2[m]), "v"(q2));
                h2[0] = fmaxf(fminf(g2[0], x2[0]), 0.0f);
                h2[1] = fmaxf(fminf(g2[1], x2[1]), 0.0f);
                asm("v_pk_add_f32 %0, %0, %1" : "+v"(s2[m]) : "v"(h2));
            }
        }

        float st = 0.0f;
        #pragma unroll
        for (int m = 0; m < IPT; ++m) st += s2[m][0] + s2[m][1];
        #pragma unroll
        for (int off = 32; off; off >>= 1) st += __shfl_down(st, off);

        const int wave = tid >> 6;
        if ((tid & 63) == 0) wsum[wave] = st;
        __syncthreads();
        if (tid == 0) {
            float b = 0.0f;
            #pragma unroll
            for (int w = 0; w < BLOCK / 64; ++w) b += wsum[w];
            partials[blockIdx.x] = b;                  // plain store
        }
    }
}

// kernel 2: tiny reduce + analytic count + divide.
__global__ __launch_bounds__(BLOCK) void prl_final(
    const float* __restrict__ partials, int npair,
    const int* __restrict__ hist, int n, float* __restrict__ out)
{
    __shared__ double wsum[BLOCK / 64];
    __shared__ int    hv[NBIN];
    const int tid = threadIdx.x;

    double s = 0.0;
    for (int i = tid; i < npair; i += BLOCK) s += (double)partials[i];
    #pragma unroll
    for (int off = 32; off; off >>= 1) s += __shfl_down(s, off);
    if ((tid & 63) == 0) wsum[tid >> 6] = s;

    if (tid < NBIN) {
        int h = 0;
        #pragma unroll
        for (int b = 0; b < NHB; ++b) h += hist[b * NBIN + tid];
        hv[tid] = h;
    }
    __syncthreads();

    if (tid == 0) {
        double tot = 0.0;
        #pragma unroll
        for (int w = 0; w < BLOCK / 64; ++w) tot += wsum[w];
        long long sq = 0;
        #pragma unroll
        for (int v = 0; v < NBIN; ++v) { const long long h = hv[v]; sq += h * h; }
        const long long cnt = ((long long)n * (long long)n - sq) / 2;  // #(t_i<t_j)
        out[0] = (cnt > 0) ? (float)(tot / (double)cnt) : 0.0f;
    }
}

extern "C" void kernel_launch(void* const* d_in, const int* in_sizes, int n_in,
                              void* d_out, int out_size, void* d_ws, size_t ws_size,
                              hipStream_t stream) {
    const float* pred = (const float*)d_in[0];
    const int*   targ = (const int*)d_in[1];
    float*       out  = (float*)d_out;
    const int    n    = in_sizes[0];

    const int gx    = (n + ITILE - 1) / ITILE;   // 4   for n=8192
    const int gy    = (n + TJ - 1) / TJ;         // 128
    const int npair = gx * gy;                   // 512

    float* partials = (float*)d_ws;
    int*   hist     = (int*)((char*)d_ws + ((size_t)npair + 64) * sizeof(float));

    prl_main<<<npair + NHB, BLOCK, 0, stream>>>(pred, targ, n, gx, npair, partials, hist);
    prl_final<<<1, BLOCK, 0, stream>>>(partials, npair, hist, n, out);
}

// Round 11
// 15.629 us; speedup vs baseline: 1.3713x; 1.3713x over previous
//
#include <hip/hip_runtime.h>

#define BLOCK  256
#define IPT    8                  // i's per thread (independent acc chains)
#define ITILE  (BLOCK * IPT)      // 2048 i's per block
#define TJ     64                 // j-chunk per block
#define SUB    16                 // register-staged sub-chunk
#define TSCALE 32.0f              // > max possible |1 - pj + pi| (~9)
#define NHB    16                 // histogram blocks
#define NBIN   20                 // targets in [0, 20)

// kernel 1: blocks [0, npair) do pair tiles; blocks [npair, npair+NHB) histogram.
// All outputs are plain stores -> no init / memset / atomics needed.
__global__ __launch_bounds__(BLOCK) void prl_main(
    const float* __restrict__ pred, const int* __restrict__ targ,
    int n, int gx, int npair,
    float* __restrict__ partials,     // [npair]
    int*   __restrict__ hist)         // [NHB * NBIN]
{
    const int tid = threadIdx.x;

    if ((int)blockIdx.x >= npair) {
        // ---------- ballot-popcount histogram block (no atomics) ----------
        const int hb   = blockIdx.x - npair;
        const int wave = tid >> 6;
        const int lane = tid & 63;

        int c[NBIN];
        #pragma unroll
        for (int v = 0; v < NBIN; ++v) c[v] = 0;

        const int CHUNK = NHB * BLOCK * 2;            // elems per grid-iteration
        const int iters = (n + CHUNK - 1) / CHUNK;    // uniform for all waves
        for (int it = 0; it < iters; ++it) {
            const int i0 = it * CHUNK + hb * BLOCK * 2 + tid * 2;
            const int t0 = (i0     < n) ? targ[i0]     : -1;
            const int t1 = (i0 + 1 < n) ? targ[i0 + 1] : -1;
            #pragma unroll
            for (int v = 0; v < NBIN; ++v)
                c[v] += __popcll(__ballot(t0 == v)) + __popcll(__ballot(t1 == v));
        }

        __shared__ int whist[BLOCK / 64][NBIN];
        if (lane == 0) {
            #pragma unroll
            for (int v = 0; v < NBIN; ++v) whist[wave][v] = c[v];
        }
        __syncthreads();
        if (tid < NBIN) {
            int h = 0;
            #pragma unroll
            for (int w = 0; w < BLOCK / 64; ++w) h += whist[w][tid];
            hist[hb * NBIN + tid] = h;                 // plain store
        }
    } else {
        // ---------- pair tile block ----------
        __shared__ float2 sj[TJ];            // (q = 1-pj, F = q + 32*tj - 32)
        __shared__ float  wsum[BLOCK / 64];
        const int bx = blockIdx.x % gx;
        const int by = blockIdx.x / gx;
        const int i0 = bx * ITILE;
        const int j0 = by * TJ;

        float pi[IPT], Ei[IPT], s[IPT];
        #pragma unroll
        for (int m = 0; m < IPT; ++m) {
            const int i = i0 + m * BLOCK + tid;
            if (i < n) {
                const float p = pred[i];
                pi[m] = p;
                Ei[m] = __fmaf_rn(-TSCALE, (float)targ[i], p);     // p - 32*t
            } else {
                pi[m] = 0.0f; Ei[m] = -1.0e9f;                     // never contributes
            }
            s[m] = 0.0f;
        }

        if (tid < TJ) {
            const int j = j0 + tid;
            float q, F;
            if (j < n) {
                const float pj = pred[j];
                q = 1.0f - pj;
                F = __fmaf_rn(TSCALE, (float)targ[j], q - TSCALE); // q + 32*t - 32
            } else {
                q = 0.0f; F = -1.0e9f;                             // never contributes
            }
            sj[tid] = make_float2(q, F);
        }
        __syncthreads();

        #pragma unroll
        for (int sub = 0; sub < TJ / SUB; ++sub) {
            float2 r[SUB];
            #pragma unroll
            for (int k = 0; k < SUB; ++k) r[k] = sj[sub * SUB + k];   // batched ds_reads
            #pragma unroll
            for (int k = 0; k < SUB; ++k) {
                const float qk = r[k].x;
                const float Fk = r[k].y;
                #pragma unroll
                for (int m = 0; m < IPT; ++m) {
                    const float g = Ei[m] + Fk;        // x + 32*(tj-ti-1)
                    const float x = pi[m] + qk;        // 1 - (pj - pi)
                    s[m] += fmaxf(fminf(g, x), 0.0f);  // hinge iff ti < tj
                }
            }
        }

        float st = 0.0f;
        #pragma unroll
        for (int m = 0; m < IPT; ++m) st += s[m];
        #pragma unroll
        for (int off = 32; off; off >>= 1) st += __shfl_down(st, off);

        const int wave = tid >> 6;
        if ((tid & 63) == 0) wsum[wave] = st;
        __syncthreads();
        if (tid == 0) {
            float b = 0.0f;
            #pragma unroll
            for (int w = 0; w < BLOCK / 64; ++w) b += wsum[w];
            partials[blockIdx.x] = b;                  // plain store
        }
    }
}

// kernel 2: tiny reduce + analytic count + divide.
__global__ __launch_bounds__(BLOCK) void prl_final(
    const float* __restrict__ partials, int npair,
    const int* __restrict__ hist, int n, float* __restrict__ out)
{
    __shared__ double wsum[BLOCK / 64];
    __shared__ int    hv[NBIN];
    const int tid = threadIdx.x;

    double s = 0.0;
    for (int i = tid; i < npair; i += BLOCK) s += (double)partials[i];
    #pragma unroll
    for (int off = 32; off; off >>= 1) s += __shfl_down(s, off);
    if ((tid & 63) == 0) wsum[tid >> 6] = s;

    if (tid < NBIN) {
        int h = 0;
        #pragma unroll
        for (int b = 0; b < NHB; ++b) h += hist[b * NBIN + tid];
        hv[tid] = h;
    }
    __syncthreads();

    if (tid == 0) {
        double tot = 0.0;
        #pragma unroll
        for (int w = 0; w < BLOCK / 64; ++w) tot += wsum[w];
        long long sq = 0;
        #pragma unroll
        for (int v = 0; v < NBIN; ++v) { const long long h = hv[v]; sq += h * h; }
        const long long cnt = ((long long)n * (long long)n - sq) / 2;  // #(t_i<t_j)
        out[0] = (cnt > 0) ? (float)(tot / (double)cnt) : 0.0f;
    }
}

extern "C" void kernel_launch(void* const* d_in, const int* in_sizes, int n_in,
                              void* d_out, int out_size, void* d_ws, size_t ws_size,
                              hipStream_t stream) {
    const float* pred = (const float*)d_in[0];
    const int*   targ = (const int*)d_in[1];
    float*       out  = (float*)d_out;
    const int    n    = in_sizes[0];

    float* partials = (float*)d_ws;
    int*   hist     = (int*)((char*)d_ws + ((size_t)((n + ITILE - 1) / ITILE) *
                                            ((n + TJ - 1) / TJ) + 64) * sizeof(float));

    const int gx    = (n + ITILE - 1) / ITILE;   // 4   for n=8192
    const int gy    = (n + TJ - 1) / TJ;         // 128
    const int npair = gx * gy;                   // 512

    prl_main<<<npair + NHB, BLOCK, 0, stream>>>(pred, targ, n, gx, npair, partials, hist);
    prl_final<<<1, BLOCK, 0, stream>>>(partials, npair, hist, n, out);
}